// Round 6
// baseline (256.122 us; speedup 1.0000x reference)
//
#include <hip/hip_runtime.h>
#include <hip/hip_bf16.h>
#include <cmath>

// GATv2 encoder, 3 layers, d=64, f32 in/out.
//   1. dst-CSR build via two-level partition:
//      coarse (1024-dst buckets, per-block LDS hist + contiguous runs -> no
//      write amplification), then per-coarse-bucket fine CSR (LDS hist[1024]
//      + scan + L2-local scatter; csr_src stored as ushort).
//   2. per layer: transform (xlh = bf16(h@Wl+bl) gather table, xr = h@Wr+br),
//      then edge aggregation: 4 nodes/wave, 16-lane groups, group-local online
//      softmax over 8-edge chunks (8 gathers in flight/group) with prefetched
//      src indices, bf16 gathers, fused bias+ReLU+residual.

#define D 64
#define CB 10              // coarse bucket = 1024 dsts (dst >> CB); N <= 65536
#define NBLK 512           // persistent blocks for coarse hist/scatter

// ---------------- CSR build ----------------

// C1: per-block coarse histogram. ghist[c*NBLK + blk] = count.
__global__ __launch_bounds__(256) void hist_coarse_kernel(
    const int* __restrict__ ei, int* __restrict__ ghist, int E, int N, int NC) {
  __shared__ int h[64];
  int tid = threadIdx.x, blk = blockIdx.x;
  if (tid < 64) h[tid] = 0;
  __syncthreads();
  for (int eid = blk * 256 + tid; eid < E + N; eid += NBLK * 256) {
    int d = (eid < E) ? ei[E + eid] : (eid - E);
    atomicAdd(&h[d >> CB], 1);
  }
  __syncthreads();
  if (tid < NC) ghist[tid * NBLK + blk] = h[tid];
}

// C2: exclusive scan of M = NC*NBLK counts in place; emit cbase[c] (+ cbase[NC]).
__global__ __launch_bounds__(1024) void scan_coarse_kernel(
    int* __restrict__ g, int* __restrict__ cbase, int M, int NC, int EP) {
  int tid = threadIdx.x;
  int chunk = (M + 1023) / 1024;
  int beg = tid * chunk;
  int end = min(M, beg + chunk);
  int sum = 0;
  for (int i = beg; i < end; ++i) sum += g[i];
  int lane = tid & 63, w = tid >> 6;
  int v = sum;
#pragma unroll
  for (int o = 1; o < 64; o <<= 1) {
    int t = __shfl_up(v, o, 64);
    if (lane >= o) v += t;
  }
  __shared__ int wsum[16], woff[16];
  if (lane == 63) wsum[w] = v;
  __syncthreads();
  if (tid == 0) { int r = 0; for (int i = 0; i < 16; ++i) { woff[i] = r; r += wsum[i]; } }
  __syncthreads();
  int run = woff[w] + (v - sum);
  for (int i = beg; i < end; ++i) {
    int old = g[i];
    g[i] = run;
    if ((i & (NBLK - 1)) == 0) cbase[i / NBLK] = run;
    run += old;
  }
  if (tid == 0) cbase[NC] = EP;
}

// C3: coarse scatter. Same grid-stride mapping as C1; per-(block,bucket) runs
// are ~34 contiguous records -> full-line writes. rec = (dst&1023)<<16 | src.
__global__ __launch_bounds__(256) void scatter_coarse_kernel(
    const int* __restrict__ ei, const int* __restrict__ g,
    unsigned* __restrict__ rec, int E, int N, int NC) {
  __shared__ int cur[64];
  int tid = threadIdx.x, blk = blockIdx.x;
  if (tid < NC) cur[tid] = g[tid * NBLK + blk];
  __syncthreads();
  for (int eid = blk * 256 + tid; eid < E + N; eid += NBLK * 256) {
    int s, d;
    if (eid < E) { s = ei[eid]; d = ei[E + eid]; }
    else         { s = d = eid - E; }
    int pos = atomicAdd(&cur[d >> CB], 1);
    rec[pos] = ((unsigned)(d & ((1 << CB) - 1)) << 16) | (unsigned)s;
  }
}

// C4: one block per coarse bucket: LDS hist of 1024 dsts -> scan -> rowptr +
// scatter (ushort src) within the bucket's contiguous (L2-local) region.
__global__ __launch_bounds__(1024) void buildcsr2_kernel(
    const unsigned* __restrict__ rec, const int* __restrict__ cbase,
    int* __restrict__ rowptr, unsigned short* __restrict__ csr_src,
    int N, int EP) {
  int c = blockIdx.x, tid = threadIdx.x;
  int bb = cbase[c], be = cbase[c + 1];
  __shared__ int hist[1024], cur[1024];
  hist[tid] = 0;
  __syncthreads();
  for (int p = bb + tid; p < be; p += 1024)
    atomicAdd(&hist[rec[p] >> 16], 1);
  __syncthreads();
  int dv = hist[tid];
  int lane = tid & 63, w = tid >> 6;
  int inc = dv;
#pragma unroll
  for (int o = 1; o < 64; o <<= 1) {
    int t = __shfl_up(inc, o, 64);
    if (lane >= o) inc += t;
  }
  __shared__ int wsum[16], woff[16];
  if (lane == 63) wsum[w] = inc;
  __syncthreads();
  if (tid == 0) { int r = 0; for (int i = 0; i < 16; ++i) { woff[i] = r; r += wsum[i]; } }
  __syncthreads();
  int excl = woff[w] + inc - dv;
  cur[tid] = excl;
  int node = (c << CB) + tid;
  if (node < N) rowptr[node] = bb + excl;
  if (c == 0 && tid == 0) rowptr[N] = EP;
  __syncthreads();
  for (int p = bb + tid; p < be; p += 1024) {
    unsigned r = rec[p];
    int pos = bb + atomicAdd(&cur[r >> 16], 1);
    csr_src[pos] = (unsigned short)(r & 0xFFFFu);
  }
}

// ---------------- transform: xlh = bf16(h@Wl+bl), xr = h@Wr+br ----------------

__device__ __forceinline__ unsigned short f2bf(float f) {
  unsigned u = __float_as_uint(f);
  return (unsigned short)((u + 0x7FFFu + ((u >> 16) & 1u)) >> 16);  // RNE
}

__global__ __launch_bounds__(256) void transform_kernel(
    const float* __restrict__ h,
    const float* __restrict__ Wl, const float* __restrict__ bl,
    const float* __restrict__ Wr, const float* __restrict__ br,
    unsigned short* __restrict__ xlh, float* __restrict__ xr, int N) {
  __shared__ float hs[16][D];
  int tid = threadIdx.x;
  int j = tid & 63;
  float wl[D], wr[D];
#pragma unroll
  for (int k = 0; k < D; ++k) {
    wl[k] = Wl[k * D + j];
    wr[k] = Wr[k * D + j];
  }
  int node0 = blockIdx.x * 16;
  for (int i = tid; i < 16 * D; i += 256) {
    int n = node0 + (i >> 6);
    hs[i >> 6][i & 63] = (n < N) ? h[(size_t)n * D + (i & 63)] : 0.f;
  }
  __syncthreads();
  float blj = bl[j], brj = br[j];
  int nl = tid >> 6;
  for (int g = 0; g < 4; ++g) {
    int local = nl * 4 + g;
    int n = node0 + local;
    float al = blj, ar = brj;
#pragma unroll
    for (int k4 = 0; k4 < D / 4; ++k4) {
      float4 hv = *reinterpret_cast<const float4*>(&hs[local][k4 * 4]);
      al = fmaf(hv.x, wl[k4 * 4 + 0], al);
      ar = fmaf(hv.x, wr[k4 * 4 + 0], ar);
      al = fmaf(hv.y, wl[k4 * 4 + 1], al);
      ar = fmaf(hv.y, wr[k4 * 4 + 1], ar);
      al = fmaf(hv.z, wl[k4 * 4 + 2], al);
      ar = fmaf(hv.z, wr[k4 * 4 + 2], ar);
      al = fmaf(hv.w, wl[k4 * 4 + 3], al);
      ar = fmaf(hv.w, wr[k4 * 4 + 3], ar);
    }
    if (n < N) {
      xlh[(size_t)n * D + j] = f2bf(al);
      xr[(size_t)n * D + j] = ar;
    }
  }
}

// ---------------- edge aggregation ----------------
// Wave = 4 nodes; 16-lane group per node (float4 features/lane, bf16 gathers).
// 8-edge chunks: 8 gathers in flight per group (32/wave); next 16 src indices
// prefetched before consuming the current batch. q[] kept packed (uint2),
// unpacked twice (score pass + accumulate pass) to save VGPRs.

__global__ __launch_bounds__(256) void edge_kernel(
    const unsigned short* __restrict__ xlh, const float* __restrict__ xr,
    const float* __restrict__ h_in, const int* __restrict__ rowptr,
    const unsigned short* __restrict__ csr_src, const float* __restrict__ att,
    const float* __restrict__ bias, float* __restrict__ h_out, int N) {
  int wv = (blockIdx.x * blockDim.x + threadIdx.x) >> 6;
  int lane = threadIdx.x & 63;
  int g = lane >> 4, l16 = lane & 15;
  int v = wv * 4 + g;
  if (v >= N) return;
  float4 xr4 = *reinterpret_cast<const float4*>(&xr[(size_t)v * D + l16 * 4]);
  float4 at4 = *reinterpret_cast<const float4*>(&att[l16 * 4]);
  int beg = rowptr[v], end = rowptr[v + 1];
  int deg = end - beg;                       // >= 1 (self-loop)
  int glane0 = g << 4;
  float m = -INFINITY, s = 0.f;
  float ax = 0.f, ay = 0.f, az = 0.f, aw = 0.f;
  int us = csr_src[min(beg + l16, end - 1)]; // first 16 srcs
  for (int sc = 0; sc < deg; sc += 16) {
    int us_cur = us;
    if (sc + 16 < deg)                       // prefetch next batch's indices
      us = csr_src[min(beg + sc + 16 + l16, end - 1)];
    int nt = min(16, deg - sc);
    for (int cc = 0; cc < nt; cc += 8) {
      int nn = nt - cc;                      // valid edges in this chunk (1..8)
      uint2 q[8];
      float p[8];
      // issue up to 8 independent gathers
#pragma unroll
      for (int k = 0; k < 8; ++k) {
        if (k < nn) {
          int u = __shfl(us_cur, glane0 + cc + k, 64);
          q[k] = *reinterpret_cast<const uint2*>(&xlh[(size_t)u * D + l16 * 4]);
        }
      }
      // score pass
#pragma unroll
      for (int k = 0; k < 8; ++k) {
        float pp = -INFINITY;
        if (k < nn) {
          float t0 = __uint_as_float(q[k].x << 16) + xr4.x;
          float t1 = __uint_as_float(q[k].x & 0xFFFF0000u) + xr4.y;
          float t2 = __uint_as_float(q[k].y << 16) + xr4.z;
          float t3 = __uint_as_float(q[k].y & 0xFFFF0000u) + xr4.w;
          t0 = fmaxf(t0, 0.2f * t0);         // leaky_relu slope 0.2
          t1 = fmaxf(t1, 0.2f * t1);
          t2 = fmaxf(t2, 0.2f * t2);
          t3 = fmaxf(t3, 0.2f * t3);
          pp = t0 * at4.x + t1 * at4.y + t2 * at4.z + t3 * at4.w;
          pp += __shfl_xor(pp, 1, 64);       // 16-lane group reduce
          pp += __shfl_xor(pp, 2, 64);
          pp += __shfl_xor(pp, 4, 64);
          pp += __shfl_xor(pp, 8, 64);
        }
        p[k] = pp;
      }
      float pm = p[0];
#pragma unroll
      for (int k = 1; k < 8; ++k) pm = fmaxf(pm, p[k]);
      float mn = fmaxf(m, pm);
      float a = __expf(m - mn);              // first chunk: exp(-inf)=0
      float sw = 0.f;
#pragma unroll
      for (int k = 0; k < 8; ++k) { p[k] = __expf(p[k] - mn); sw += p[k]; }
      s = s * a + sw;
      ax *= a; ay *= a; az *= a; aw *= a;
      // accumulate pass (re-unpack)
#pragma unroll
      for (int k = 0; k < 8; ++k) {
        if (k < nn) {
          ax = fmaf(p[k], __uint_as_float(q[k].x << 16), ax);
          ay = fmaf(p[k], __uint_as_float(q[k].x & 0xFFFF0000u), ay);
          az = fmaf(p[k], __uint_as_float(q[k].y << 16), az);
          aw = fmaf(p[k], __uint_as_float(q[k].y & 0xFFFF0000u), aw);
        }
      }
      m = mn;
    }
  }
  float inv = 1.f / s;
  float4 b4v = *reinterpret_cast<const float4*>(&bias[l16 * 4]);
  float4 hv  = *reinterpret_cast<const float4*>(&h_in[(size_t)v * D + l16 * 4]);
  float4 o;
  o.x = fmaxf(ax * inv + b4v.x, 0.f) + hv.x;
  o.y = fmaxf(ay * inv + b4v.y, 0.f) + hv.y;
  o.z = fmaxf(az * inv + b4v.z, 0.f) + hv.z;
  o.w = fmaxf(aw * inv + b4v.w, 0.f) + hv.w;
  *reinterpret_cast<float4*>(&h_out[(size_t)v * D + l16 * 4]) = o;
}

// ---------------- launch ----------------

extern "C" void kernel_launch(void* const* d_in, const int* in_sizes, int n_in,
                              void* d_out, int out_size, void* d_ws, size_t ws_size,
                              hipStream_t stream) {
  const float* x    = (const float*)d_in[0];
  const int*   ei   = (const int*)d_in[1];
  const float* Wl   = (const float*)d_in[2];
  const float* bl   = (const float*)d_in[3];
  const float* Wr   = (const float*)d_in[4];
  const float* br   = (const float*)d_in[5];
  const float* att  = (const float*)d_in[6];
  const float* bias = (const float*)d_in[7];

  int N = in_sizes[0] / D;
  int E = in_sizes[1] / 2;
  int L = in_sizes[2] / (D * D);
  int EP = E + N;
  int NC = (N + (1 << CB) - 1) >> CB;   // coarse buckets (<= 64)
  int M = NC * NBLK;

  float* xr = (float*)d_ws;
  float* hA = xr + (size_t)N * D;
  float* hB = hA + (size_t)N * D;
  unsigned short* xlh = (unsigned short*)(hB + (size_t)N * D);
  unsigned* rec = (unsigned*)(xlh + (size_t)N * D);
  unsigned short* csr_src = (unsigned short*)(rec + EP);
  int* rowptr   = (int*)(csr_src + ((EP + 1) & ~1));
  int* ghist    = rowptr + (N + 1);
  int* cbase    = ghist + M;

  // CSR build (graph is layer-invariant: build once per call; every ghist/cbase
  // slot is written each call, so no memset needed)
  hist_coarse_kernel<<<NBLK, 256, 0, stream>>>(ei, ghist, E, N, NC);
  scan_coarse_kernel<<<1, 1024, 0, stream>>>(ghist, cbase, M, NC, EP);
  scatter_coarse_kernel<<<NBLK, 256, 0, stream>>>(ei, ghist, rec, E, N, NC);
  buildcsr2_kernel<<<NC, 1024, 0, stream>>>(rec, cbase, rowptr, csr_src, N, EP);

  int nwaves = (N + 3) / 4;                 // 4 nodes per wave
  int nblocks = (nwaves * 64 + 255) / 256;
  const float* h_in = x;
  for (int l = 0; l < L; ++l) {
    float* h_out = (l == L - 1) ? (float*)d_out : ((l % 2 == 0) ? hA : hB);
    transform_kernel<<<(N + 15) / 16, 256, 0, stream>>>(
        h_in, Wl + (size_t)l * D * D, bl + (size_t)l * D,
        Wr + (size_t)l * D * D, br + (size_t)l * D, xlh, xr, N);
    edge_kernel<<<nblocks, 256, 0, stream>>>(
        xlh, xr, h_in, rowptr, csr_src, att + (size_t)l * D,
        bias + (size_t)l * D, h_out, N);
    h_in = h_out;
  }
}